// Round 6
// baseline (156.261 us; speedup 1.0000x reference)
//
#include <hip/hip_runtime.h>
#include <cstddef>

#define B   4
#define D   512
#define T   2048
#define H   8
#define DH  64
#define NEG_SLOPE 0.2f
#define EPS 1e-6f
#define LOG2E 1.44269504088896340736f

typedef __attribute__((ext_vector_type(8))) short short8;   // 8 x bf16 (4 VGPRs)
typedef __attribute__((ext_vector_type(4))) float float4v;  // 4 x f32

__device__ __forceinline__ float bf2f(ushort u) {
    unsigned int x = ((unsigned int)u) << 16;
    return __builtin_bit_cast(float, x);
}
__device__ __forceinline__ ushort f2bf(float f) {
    unsigned int x = __builtin_bit_cast(unsigned int, f);
    x = x + 0x7fffu + ((x >> 16) & 1u);   // round-to-nearest-even
    return (ushort)(x >> 16);
}

// -----------------------------------------------------------------------------
// Kernel A: 64x64-tiled transpose fp32 -> bf16, optional leaky-ReLU.
// Block (0,0,0) also zeroes zbuf (ssq accumulator) when zbuf != nullptr.
// -----------------------------------------------------------------------------
__global__ __launch_bounds__(256) void transpose_lrelu(const float* __restrict__ src,
                                                       ushort* __restrict__ dst,
                                                       int src_ld, int dst_ld,
                                                       size_t src_mstride, size_t dst_mstride,
                                                       int do_lrelu,
                                                       float* __restrict__ zbuf, int zcount) {
    const int tid = threadIdx.x;
    if (zbuf != nullptr && blockIdx.x == 0 && blockIdx.y == 0 && blockIdx.z == 0) {
        for (int i = tid; i < zcount; i += 256) zbuf[i] = 0.f;
    }

    const int c0 = blockIdx.x * 64, r0 = blockIdx.y * 64;
    const float* s = src + blockIdx.z * src_mstride + (size_t)r0 * src_ld + c0;
    ushort*      d = dst + blockIdx.z * dst_mstride + (size_t)c0 * dst_ld + r0;

    __shared__ float Ls[64][68];

    const int rl = tid >> 4, c4 = (tid & 15) * 4;
    #pragma unroll
    for (int p = 0; p < 4; ++p) {
        float4 v = *(const float4*)(s + (size_t)(rl + p * 16) * src_ld + c4);
        if (do_lrelu) {
            v.x = fmaxf(v.x, NEG_SLOPE * v.x);
            v.y = fmaxf(v.y, NEG_SLOPE * v.y);
            v.z = fmaxf(v.z, NEG_SLOPE * v.z);
            v.w = fmaxf(v.w, NEG_SLOPE * v.w);
        }
        *(float4*)&Ls[rl + p * 16][c4] = v;
    }
    __syncthreads();

    const int tl = tid >> 2;
    #pragma unroll
    for (int it = 0; it < 2; ++it) {
        int ch = (tid & 3) + it * 4;
        ushort o[8];
        #pragma unroll
        for (int j = 0; j < 8; ++j) o[j] = f2bf(Ls[ch * 8 + j][tl]);
        *(uint4*)(d + (size_t)tl * dst_ld + ch * 8) = *(uint4*)o;
    }
}

// -----------------------------------------------------------------------------
// Kernel B: QKV GEMM via bf16 MFMA.
// Per-block operand orientation so C-regs match output layout:
//   V blocks  (blockIdx.y>=8): C[t][gd]   -> lane has 4 consecutive t  (vT[dd][t])
//   Q/K blocks (blockIdx.y<8): C^T[gd][t] -> lane has 4 consecutive dd (hb[t][dh])
// Epilogue: wave-private LDS retile (reusing main tiles) -> b128 coalesced
// stores; ssq via shuffle-reduce + masked atomics.
// -----------------------------------------------------------------------------
__global__ __launch_bounds__(256) void qkv_mm(const ushort* __restrict__ xT,
                                              const ushort* __restrict__ WT,
                                              ushort* __restrict__ hb,
                                              ushort* __restrict__ vT,
                                              float* __restrict__ ssq) {
    const int tid = threadIdx.x, wave = tid >> 6, lane = tid & 63;
    const int quad = lane >> 4, l16 = lane & 15;
    const int wr = wave >> 1, wc = wave & 1;
    const int t0  = blockIdx.x * 128;
    const int gd0 = blockIdx.y * 128;
    const int b   = blockIdx.z;

    __shared__ ushort SMEM[2 * 128 * 64];   // 32 KB: At | Bt, later E-scratch
    ushort* At = SMEM;
    ushort* Bt = SMEM + 128 * 64;

    const ushort* xb = xT + (size_t)b * T * D + (size_t)t0 * D;
    const ushort* wb = WT + (size_t)gd0 * D;

    const int srow = lane >> 3;
    const int csrc = (lane & 7) ^ srow;

    const bool is_v = (blockIdx.y >= 8);
    // m-dim / n-dim LDS sources per orientation
    const ushort* Asrc = is_v ? At : Bt;
    const ushort* Bsrc = is_v ? Bt : At;
    const int arow0 = is_v ? wr * 64 : wc * 64;
    const int brow0 = is_v ? wc * 64 : wr * 64;

    float4v acc[4][4];
    #pragma unroll
    for (int i = 0; i < 4; ++i)
        #pragma unroll
        for (int j = 0; j < 4; ++j) acc[i][j] = (float4v){0.f, 0.f, 0.f, 0.f};

    for (int k0 = 0; k0 < D; k0 += 64) {
        #pragma unroll
        for (int i = 0; i < 4; ++i) {
            int rbase = wave * 32 + i * 8;
            int row = rbase + srow;
            const ushort* ga = xb + (size_t)row * D + k0 + csrc * 8;
            const ushort* gb = wb + (size_t)row * D + k0 + csrc * 8;
            __builtin_amdgcn_global_load_lds(
                (const __attribute__((address_space(1))) unsigned int*)ga,
                (__attribute__((address_space(3))) unsigned int*)&At[rbase * 64], 16, 0, 0);
            __builtin_amdgcn_global_load_lds(
                (const __attribute__((address_space(1))) unsigned int*)gb,
                (__attribute__((address_space(3))) unsigned int*)&Bt[rbase * 64], 16, 0, 0);
        }
        __syncthreads();

        #pragma unroll
        for (int kh = 0; kh < 2; ++kh) {
            short8 aF[4], bF[4];
            #pragma unroll
            for (int mt = 0; mt < 4; ++mt) {
                int row = arow0 + mt * 16 + l16;
                aF[mt] = *(const short8*)&Asrc[row * 64 + (((kh * 4 + quad) ^ (l16 & 7)) * 8)];
            }
            #pragma unroll
            for (int nt = 0; nt < 4; ++nt) {
                int row = brow0 + nt * 16 + l16;
                bF[nt] = *(const short8*)&Bsrc[row * 64 + (((kh * 4 + quad) ^ (l16 & 7)) * 8)];
            }
            #pragma unroll
            for (int mt = 0; mt < 4; ++mt)
                #pragma unroll
                for (int nt = 0; nt < 4; ++nt)
                    acc[mt][nt] = __builtin_amdgcn_mfma_f32_16x16x32_bf16(
                        aF[mt], bF[nt], acc[mt][nt], 0, 0, 0);
        }
        __syncthreads();   // last iter: also releases SMEM for epilogue reuse
    }

    // ---- epilogue: C -> wave-private LDS (8 KB) -> coalesced b128 stores ----
    const int g  = blockIdx.y * 2 + wc;      // 0..23
    const int n  = g >> 3, hh = g & 7;
    const int ch = ((n * B + b) * H + hh) * 64;

    ushort* E = SMEM + wave * 4096;          // 64 rows x 64 cols, 16B-chunk XOR swizzle

    // write: row = n-dim (V: dd, QK: t) = nt*16+l16; chunk = m-dim/8
    #pragma unroll
    for (int mt = 0; mt < 4; ++mt) {
        #pragma unroll
        for (int nt = 0; nt < 4; ++nt) {
            float4v c = acc[mt][nt];
            ushort4 pk;
            pk.x = f2bf(c[0]); pk.y = f2bf(c[1]);
            pk.z = f2bf(c[2]); pk.w = f2bf(c[3]);
            int row   = nt * 16 + l16;
            int chunk = mt * 2 + (quad >> 1);
            int pos   = chunk ^ (l16 & 7);
            *(ushort4*)&E[row * 64 + pos * 8 + (quad & 1) * 4] = pk;
        }
    }
    // no barrier: E is wave-private

    const int rsub = lane >> 3;              // row-in-group 0..7
    const int csub = lane & 7;               // ordered chunk 0..7
    const int posr = csub ^ rsub;            // swizzled read position

    if (!is_v) {
        // rows = t, cols = dd  ->  hb[t][dh] rows, 1KB linear per instr
        ushort* hbase = hb + (((size_t)n * B + b) * H + hh) * (size_t)T * DH
                        + (size_t)(t0 + wr * 64) * DH;
        float sq8[8] = {0.f, 0.f, 0.f, 0.f, 0.f, 0.f, 0.f, 0.f};
        #pragma unroll
        for (int i = 0; i < 8; ++i) {
            uint4 v = *(const uint4*)&E[(i * 8 + rsub) * 64 + posr * 8];
            const ushort* u = (const ushort*)&v;
            #pragma unroll
            for (int j = 0; j < 8; ++j) { float f = bf2f(u[j]); sq8[j] += f * f; }
            *(uint4*)(hbase + (size_t)(i * 8 + rsub) * DH + csub * 8) = v;
        }
        #pragma unroll
        for (int j = 0; j < 8; ++j) {
            float s = sq8[j];
            s += __shfl_xor(s, 8); s += __shfl_xor(s, 16); s += __shfl_xor(s, 32);
            if (lane < 8) atomicAdd(&ssq[ch + lane * 8 + j], s);
        }
    } else {
        // rows = dd, cols = t  ->  vT[dd][t] rows, full 128B lines per instr
        ushort* vbase = vT + ((size_t)b * H + hh) * (size_t)DH * T + (t0 + wr * 64);
        #pragma unroll
        for (int i = 0; i < 8; ++i) {
            uint4 v = *(const uint4*)&E[(i * 8 + rsub) * 64 + posr * 8];
            const ushort* u = (const ushort*)&v;
            float s = 0.f;
            #pragma unroll
            for (int j = 0; j < 8; ++j) { float f = bf2f(u[j]); s += f * f; }
            *(uint4*)(vbase + (size_t)(i * 8 + rsub) * T + csub * 8) = v;
            s += __shfl_xor(s, 1); s += __shfl_xor(s, 2); s += __shfl_xor(s, 4);
            if ((lane & 7) == 0) atomicAdd(&ssq[ch + i * 8 + rsub], s);
        }
    }
}

// -----------------------------------------------------------------------------
// Kernel C: flash attention (unchanged from round 5).
// -----------------------------------------------------------------------------
__global__ __launch_bounds__(256, 4) void flash_attn(const ushort* __restrict__ hb,
                                                     const ushort* __restrict__ vT,
                                                     const float* __restrict__ ssq,
                                                     const float* __restrict__ norm_w,
                                                     float* __restrict__ out) {
    const int tid  = threadIdx.x;
    const int wave = tid >> 6;
    const int lane = tid & 63;
    const int quad = lane >> 4;
    const int l16  = lane & 15;

    const int lin  = blockIdx.x;
    const int head = ((lin & 7) << 2) | ((lin >> 3) & 3);   // b*H+hh
    const int t0   = (lin >> 5) * 64;
    const int b    = head >> 3, hh = head & 7;

    const size_t slab = (size_t)B * H * T * DH;
    const ushort* qp = hb + (size_t)head * T * DH;
    const ushort* kp = hb + slab + (size_t)head * T * DH;
    const ushort* vp = vT + (size_t)head * DH * T;

    __shared__ ushort Kt[64 * 64];
    __shared__ ushort Vt[64 * 64];
    __shared__ ushort Pb[4][16 * 64];
    __shared__ float fqk[64], sv[64];

    if (tid < 64) {
        float nw = norm_w[0];
        float mq = ssq[(0 * B * H + head) * 64 + tid] * (1.0f / T) + EPS;
        float mk = ssq[(1 * B * H + head) * 64 + tid] * (1.0f / T) + EPS;
        float mv = ssq[(2 * B * H + head) * 64 + tid] * (1.0f / T) + EPS;
        fqk[tid] = nw * nw * rsqrtf(mq) * rsqrtf(mk) * 0.125f * LOG2E;
        sv[tid]  = nw * rsqrtf(mv);
    }
    __syncthreads();

    short8 bQ[2];
    {
        const ushort* qr = qp + (size_t)(t0 + wave * 16 + l16) * DH;
        #pragma unroll
        for (int kh = 0; kh < 2; ++kh) {
            short8 raw = *(const short8*)(qr + kh * 32 + quad * 8);
            #pragma unroll
            for (int j = 0; j < 8; ++j) {
                float f = bf2f((ushort)raw[j]) * fqk[kh * 32 + quad * 8 + j];
                bQ[kh][j] = (short)f2bf(f);
            }
        }
    }

    const int srow = lane >> 3;
    const int csrc = (lane & 7) ^ srow;
    const ushort* kA = kp + (size_t)(wave * 16 + srow) * DH + csrc * 8;
    const ushort* kB = kp + (size_t)(wave * 16 + 8 + srow) * DH + csrc * 8;
    const ushort* vA = vp + (size_t)(wave * 16 + srow) * T + csrc * 8;
    const ushort* vB = vp + (size_t)(wave * 16 + 8 + srow) * T + csrc * 8;

    float l_run = 0.f;
    float4v O[4];
    #pragma unroll
    for (int dt = 0; dt < 4; ++dt) O[dt] = (float4v){0.f, 0.f, 0.f, 0.f};

    for (int j0 = 0; j0 < T; j0 += 64) {
        __builtin_amdgcn_global_load_lds(
            (const __attribute__((address_space(1))) unsigned int*)(kA + (size_t)j0 * DH),
            (__attribute__((address_space(3))) unsigned int*)&Kt[(wave * 16) * 64], 16, 0, 0);
        __builtin_amdgcn_global_load_lds(
            (const __attribute__((address_space(1))) unsigned int*)(kB + (size_t)j0 * DH),
            (__attribute__((address_space(3))) unsigned int*)&Kt[(wave * 16 + 8) * 64], 16, 0, 0);
        __builtin_amdgcn_global_load_lds(
            (const __attribute__((address_space(1))) unsigned int*)(vA + j0),
            (__attribute__((address_space(3))) unsigned int*)&Vt[(wave * 16) * 64], 16, 0, 0);
        __builtin_amdgcn_global_load_lds(
            (const __attribute__((address_space(1))) unsigned int*)(vB + j0),
            (__attribute__((address_space(3))) unsigned int*)&Vt[(wave * 16 + 8) * 64], 16, 0, 0);
        __syncthreads();

        float4v S[4];
        #pragma unroll
        for (int mt = 0; mt < 4; ++mt) S[mt] = (float4v){0.f, 0.f, 0.f, 0.f};
        #pragma unroll
        for (int kh = 0; kh < 2; ++kh) {
            #pragma unroll
            for (int mt = 0; mt < 4; ++mt) {
                int row = mt * 16 + l16;
                short8 aK = *(const short8*)&Kt[row * 64 + (((kh * 4 + quad) ^ (row & 7)) * 8)];
                S[mt] = __builtin_amdgcn_mfma_f32_16x16x32_bf16(aK, bQ[kh], S[mt], 0, 0, 0);
            }
        }

        #pragma unroll
        for (int mt = 0; mt < 4; ++mt) {
            float p0 = __builtin_amdgcn_exp2f(S[mt][0]);
            float p1 = __builtin_amdgcn_exp2f(S[mt][1]);
            float p2 = __builtin_amdgcn_exp2f(S[mt][2]);
            float p3 = __builtin_amdgcn_exp2f(S[mt][3]);
            l_run += (p0 + p1) + (p2 + p3);
            unsigned int a0 = __builtin_bit_cast(unsigned int, p0) + 0x8000u;
            unsigned int a1 = __builtin_bit_cast(unsigned int, p1) + 0x8000u;
            unsigned int a2 = __builtin_bit_cast(unsigned int, p2) + 0x8000u;
            unsigned int a3 = __builtin_bit_cast(unsigned int, p3) + 0x8000u;
            uint2 pk;
            pk.x = __builtin_amdgcn_perm(a1, a0, 0x07060302u);
            pk.y = __builtin_amdgcn_perm(a3, a2, 0x07060302u);
            *(uint2*)&Pb[wave][l16 * 64 + (((mt * 2 + (quad >> 1)) ^ (l16 & 7)) * 8)
                               + (quad & 1) * 4] = pk;
        }

        #pragma unroll
        for (int kh = 0; kh < 2; ++kh) {
            short8 bP = *(const short8*)&Pb[wave][l16 * 64 + (((kh * 4 + quad) ^ (l16 & 7)) * 8)];
            #pragma unroll
            for (int dt = 0; dt < 4; ++dt) {
                int row = dt * 16 + l16;
                short8 aV = *(const short8*)&Vt[row * 64 + (((kh * 4 + quad) ^ (row & 7)) * 8)];
                O[dt] = __builtin_amdgcn_mfma_f32_16x16x32_bf16(aV, bP, O[dt], 0, 0, 0);
            }
        }
        __syncthreads();
    }

    float rs = l_run;
    rs += __shfl_xor(rs, 16);
    rs += __shfl_xor(rs, 32);
    float inv = 1.f / rs;
    const int t = t0 + wave * 16 + l16;
    #pragma unroll
    for (int dt = 0; dt < 4; ++dt) {
        #pragma unroll
        for (int r = 0; r < 4; ++r) {
            int dd = dt * 16 + quad * 4 + r;
            out[((size_t)b * D + hh * DH + dd) * T + t] = O[dt][r] * inv * sv[dd];
        }
    }
}

// -----------------------------------------------------------------------------
extern "C" void kernel_launch(void* const* d_in, const int* in_sizes, int n_in,
                              void* d_out, int out_size, void* d_ws, size_t ws_size,
                              hipStream_t stream) {
    const float* x      = (const float*)d_in[0];
    const float* qkv    = (const float*)d_in[1];
    const float* norm_w = (const float*)d_in[2];
    float* out = (float*)d_out;

    const size_t HB_BYTES = (size_t)2 * B * H * T * DH * 2;   // Q+K slabs
    const size_t VT_BYTES = (size_t)B * H * DH * T * 2;
    const size_t XT_BYTES = (size_t)B * T * D * 2;
    const size_t WT_BYTES = (size_t)3 * H * DH * D * 2;
    ushort* hb  = (ushort*)d_ws;
    ushort* vT  = (ushort*)((char*)d_ws + HB_BYTES);
    ushort* xT  = (ushort*)((char*)d_ws + HB_BYTES + VT_BYTES);
    ushort* WT  = (ushort*)((char*)d_ws + HB_BYTES + VT_BYTES + XT_BYTES);
    float*  ssq = (float*)((char*)d_ws + HB_BYTES + VT_BYTES + XT_BYTES + WT_BYTES);
    const int SSQ_N = 3 * B * H * DH;

    transpose_lrelu<<<dim3(T / 64, D / 64, B), 256, 0, stream>>>(
        x, xT, T, D, (size_t)D * T, (size_t)T * D, 1, ssq, SSQ_N);
    transpose_lrelu<<<dim3(DH / 64, D / 64, 3 * H), 256, 0, stream>>>(
        qkv, WT, DH, D, (size_t)D * DH, (size_t)DH * D, 0, nullptr, 0);

    qkv_mm<<<dim3(T / 128, (3 * H * DH) / 128, B), 256, 0, stream>>>(xT, WT, hb, vT, ssq);
    flash_attn<<<dim3((T / 64) * B * H), 256, 0, stream>>>(hb, vT, ssq, norm_w, out);
}